// Round 8
// baseline (65.478 us; speedup 1.0000x reference)
//
#include <hip/hip_runtime.h>
#include <hip/hip_fp16.h>
#include <cmath>

#define BB 4
#define HH 64
#define WW 64
// ---- LDS pool word-offsets (fp32 words), total 39583 w = 154.6 KiB ----
#define WINW  0         // 5*64*64 half = 10240 w : 5-row fp16 sample window
#define TFW   10240     // 64*65 = 4160 w : t_f  ; later agg
#define TCW   14400     // 64*65 = 4160 w : t_c  ; later pc out
#define TMW   18560     // 64*65 = 4160 w : t_m  ; later h1
#define SLOTW 22720     // 52*64*4 = 13312 w : {ox,oy,-,-} -> packed taps
#define SBW   36032     // 53*67 = 3551 w : scores -> mod (stride 67)
#define POOLW 39583

typedef _Float16 half2v __attribute__((ext_vector_type(2)));
__device__ inline float fdot2u(uint32_t a, uint32_t b, float c) {
    return __builtin_amdgcn_fdot2(__builtin_bit_cast(half2v, a),
                                  __builtin_bit_cast(half2v, b), c, false);
}

// ---------------- NCHW -> NHWC fp16 transpose (LDS tiled) ----------------
__global__ __launch_bounds__(256) void transpose_half(const float* __restrict__ x,
                                                      __half* __restrict__ xth) {
    int bid = blockIdx.x;
    int b = bid >> 6, y = bid & 63;
    __shared__ float tile[64][65];
    const float* xp = x + ((size_t)b * 64 * HH + y) * WW;
    #pragma unroll
    for (int k = 0; k < 16; ++k) {
        int idx = threadIdx.x + (k << 8);
        int c = idx >> 6, w = idx & 63;
        tile[c][w] = xp[(size_t)c * HH * WW + w];
    }
    __syncthreads();
    __half* op = xth + ((size_t)(b * HH + y) * WW) * 64;
    #pragma unroll
    for (int k = 0; k < 16; ++k) {
        int idx = threadIdx.x + (k << 8);
        int w = idx >> 6, c = idx & 63;
        op[(size_t)w * 64 + c] = __float2half(tile[c][w]);
    }
}

// pointwise rows: lane = pixel (64), o0 wave-uniform -> scalar weight loads
template<int RPW>
__device__ inline void pw_acc(const float* __restrict__ P, int base, int lane, int o0, int R,
                              const float* __restrict__ W, const float* __restrict__ Bv,
                              float* acc) {
    int oc[RPW];
    #pragma unroll
    for (int r = 0; r < RPW; ++r) { oc[r] = min(o0 + r, R - 1); acc[r] = Bv[oc[r]]; }
    #pragma unroll 8
    for (int k = 0; k < 64; ++k) {
        float v = P[base + k * 65 + lane];
        #pragma unroll
        for (int r = 0; r < RPW; ++r) acc[r] = fmaf(W[oc[r] * 64 + k], v, acc[r]);
    }
}

// ---------------- fused main: 1 block (16 waves, 1024 thr) per image row ----------------
__global__ __launch_bounds__(1024, 4) void crossd_main(
    const __half* __restrict__ xth, const float* __restrict__ x,
    const float* __restrict__ p_n,
    const float* __restrict__ dwf_w, const float* __restrict__ dwf_b,
    const float* __restrict__ pwf_w, const float* __restrict__ pwf_b,
    const float* __restrict__ dwc_w, const float* __restrict__ dwc_b,
    const float* __restrict__ pwc_w, const float* __restrict__ pwc_b,
    const float* __restrict__ dwm_w, const float* __restrict__ dwm_b,
    const float* __restrict__ pwm_w, const float* __restrict__ pwm_b,
    const float* __restrict__ pc_w, const float* __restrict__ pc_b,
    const float* __restrict__ w1, const float* __restrict__ b1,
    const float* __restrict__ w2, const float* __restrict__ b2,
    float* __restrict__ out)
{
    __shared__ float P[POOLW];
    uint32_t* PU = reinterpret_cast<uint32_t*>(P);
    __half*   PH = reinterpret_cast<__half*>(P);
    const int tid  = threadIdx.x;
    const int lane = tid & 63;
    const int wv   = __builtin_amdgcn_readfirstlane(tid >> 6);   // 0..15
    const int b = blockIdx.x >> 6, y = blockIdx.x & 63;
    const int ry0 = min(max(y - 1, 0), 59);                      // window rows ry0..ry0+4
    const __half* xbh = xth + (size_t)b * (HH * WW * 64);
    const uint2* xb2 = reinterpret_cast<const uint2*>(xbh);

    // ---- phase 0: stage 5-row fp16 window into LDS ----
    {
        const int px = tid >> 4, c4v = tid & 15;
        uint2* WINu = reinterpret_cast<uint2*>(P);
        #pragma unroll
        for (int j = 0; j < 5; ++j) {
            int ry = ry0 + j;
            WINu[(j * 64 + px) * 16 + c4v] = xb2[((ry << 6) + px) * 16 + c4v];
        }
    }
    __syncthreads();   // B0

    // ---- depthwise 3x3 from LDS window: wave = 4 px, lane = ch; writes 3 t-buffers ----
    {
        const int c = lane;
        float wf9[9], wc9[9], wm9[9];
        #pragma unroll
        for (int k9 = 0; k9 < 9; ++k9) {
            wf9[k9] = dwf_w[c * 9 + k9];
            wc9[k9] = dwc_w[c * 9 + k9];
            wm9[k9] = dwm_w[c * 9 + k9];
        }
        const float bf = dwf_b[c], bc = dwc_b[c], bm = dwm_b[c];
        #pragma unroll
        for (int i = 0; i < 4; ++i) {
            const int px = wv * 4 + i;
            float af = bf, ac = bc, am = bm;
            #pragma unroll
            for (int dy = 0; dy < 3; ++dy) {
                int yy = y + dy - 1;
                if (yy < 0 || yy >= HH) continue;
                int j = yy - ry0;
                #pragma unroll
                for (int dx = 0; dx < 3; ++dx) {
                    int xx = px + dx - 1;
                    if (xx < 0 || xx >= WW) continue;
                    float v = __half2float(PH[(j * 64 + xx) * 64 + c]);
                    int k = dy * 3 + dx;
                    af = fmaf(v, wf9[k], af);
                    ac = fmaf(v, wc9[k], ac);
                    am = fmaf(v, wm9[k], am);
                }
            }
            P[TFW + c * 65 + px] = af;
            P[TCW + c * 65 + px] = ac;
            P[TMW + c * 65 + px] = am;
        }
    }
    __syncthreads();   // B1

    // ---- fused f+c+m pointwise: ONE k-loop, 11 accumulators, 3 LDS reads per k ----
    {
        const int f0 = wv * 2, c0 = wv * 5, m0 = wv * 4;
        int ocF[2], ocC[5], ocM[4];
        float accF[2], accC[5], accM[4];
        #pragma unroll
        for (int r = 0; r < 2; ++r) { ocF[r] = min(f0 + r, 31); accF[r] = pwf_b[ocF[r]]; }
        #pragma unroll
        for (int r = 0; r < 5; ++r) { ocC[r] = min(c0 + r, 71); accC[r] = pwc_b[ocC[r]]; }
        #pragma unroll
        for (int r = 0; r < 4; ++r) { ocM[r] = min(m0 + r, 52); accM[r] = pwm_b[ocM[r]]; }
        #pragma unroll 4
        for (int k = 0; k < 64; ++k) {
            float vF = P[TFW + k * 65 + lane];
            float vC = P[TCW + k * 65 + lane];
            float vM = P[TMW + k * 65 + lane];
            #pragma unroll
            for (int r = 0; r < 2; ++r) accF[r] = fmaf(pwf_w[ocF[r] * 64 + k], vF, accF[r]);
            #pragma unroll
            for (int r = 0; r < 5; ++r) accC[r] = fmaf(pwc_w[ocC[r] * 64 + k], vC, accC[r]);
            #pragma unroll
            for (int r = 0; r < 4; ++r) accM[r] = fmaf(pwm_w[ocM[r] * 64 + k], vM, accM[r]);
        }
        #pragma unroll
        for (int r = 0; r < 2; ++r)
            P[SLOTW + ((f0 + r) * 64 + lane) * 4 + 0] = accF[r];
        #pragma unroll
        for (int r = 0; r < 5; ++r) {
            int rr = c0 + r;
            if (rr < 72) {
                int og = 32 + rr;
                int e = (og < 52) ? (og * 64 + lane) * 4
                                  : ((og - 52) * 64 + lane) * 4 + 1;
                P[SLOTW + e] = accC[r];
            }
        }
        #pragma unroll
        for (int r = 0; r < 4; ++r) {
            int o = m0 + r;
            if (o < 53) P[SBW + o * 67 + lane] = accM[r];
        }
    }
    __syncthreads();   // B2

    // ---- gated softmax over 52 scores (in-place in SB): lane = n, wave owns 4 px ----
    #pragma unroll
    for (int i = 0; i < 4; ++i) {
        const int px = wv * 4 + i;
        const float sp = P[SBW + 52 * 67 + px];
        float z = -1e30f;
        if (lane < 52) {
            float s  = P[SBW + lane * 67 + px];
            float sg = 1.0f / (1.0f + __expf(-(s - sp) * 10.0f));
            z = s + __logf(sg + 1e-10f);
        }
        float mx = z;
        #pragma unroll
        for (int d = 32; d >= 1; d >>= 1) mx = fmaxf(mx, __shfl_xor(mx, d));
        float e = (lane < 52) ? __expf(z - mx) : 0.0f;
        float sm = e;
        #pragma unroll
        for (int d = 32; d >= 1; d >>= 1) sm += __shfl_xor(sm, d);
        if (lane < 52) P[SBW + lane * 67 + px] = e / sm;
    }
    __syncthreads();   // B3

    // ---- coordpack: rewrite each SLOT entry as {4 u16 LDS offsets, 4 half weights} ----
    {
        const int ppx = tid & 63;
        const int g   = tid >> 6;
        for (int n = g; n < 52; n += 16) {
            const int e4 = SLOTW + (n * 64 + ppx) * 4;
            float sx = (float)ppx + p_n[n]      + P[e4 + 0];
            float sy = (float)y   + p_n[52 + n] + P[e4 + 1];
            float mo = P[SBW + n * 67 + ppx];
            float x0f = floorf(sx), y0f = floorf(sy);
            float wx1 = sx - x0f, wy1 = sy - y0f;
            float wx0 = 1.0f - wx1, wy0 = 1.0f - wy1;
            int x0 = (int)x0f, y0 = (int)y0f;
            int xi0 = min(max(x0, 0), 63), xi1 = min(max(x0 + 1, 0), 63);
            int yi0 = min(max(y0, 0), 63), yi1 = min(max(y0 + 1, 0), 63);
            bool vx0 = (x0 >= 0)  & (x0 <= 63);
            bool vx1 = (x0 >= -1) & (x0 <= 62);
            bool vy0 = (y0 >= 0)  & (y0 <= 63);
            bool vy1 = (y0 >= -1) & (y0 <= 62);
            float m00 = (vy0 & vx0) ? mo * wy0 * wx0 : 0.0f;
            float m01 = (vy0 & vx1) ? mo * wy0 * wx1 : 0.0f;
            float m10 = (vy1 & vx0) ? mo * wy1 * wx0 : 0.0f;
            float m11 = (vy1 & vx1) ? mo * wy1 * wx1 : 0.0f;
            int j0 = yi0 - ry0, j1 = yi1 - ry0;
            uint32_t w0, w1;
            if ((j0 >= 0) & (j1 <= 4)) {
                w0 = (uint32_t)((j0 * 64 + xi0) * 128) | ((uint32_t)((j0 * 64 + xi1) * 128) << 16);
                w1 = (uint32_t)((j1 * 64 + xi0) * 128) | ((uint32_t)((j1 * 64 + xi1) * 128) << 16);
            } else {
                w0 = 0xFFFFFFFFu;
                w1 = (uint32_t)((yi0 << 6) | xi0) | ((uint32_t)((yi1 << 6) | xi1) << 16);
            }
            __half2 hA = __floats2half2_rn(m00, m01);
            __half2 hB = __floats2half2_rn(m10, m11);
            uint4 pkw;
            pkw.x = w0; pkw.y = w1;
            pkw.z = *reinterpret_cast<uint32_t*>(&hA);
            pkw.w = *reinterpret_cast<uint32_t*>(&hB);
            *reinterpret_cast<uint4*>(&PU[e4]) = pkw;
        }
    }
    __syncthreads();   // B4

    // ---- 52-tap gather from LDS window: perm + fdot2; lane = (px_sub, ch_quad) ----
    {
        const int sub = lane >> 4;      // 0..3
        const int c4  = lane & 15;      // channel quad
        const int spx = wv * 4 + sub;
        const int c4b = c4 * 8;
        const char* Pb = reinterpret_cast<const char*>(P);
        float4 agg = make_float4(0.f, 0.f, 0.f, 0.f);
        #pragma unroll 4
        for (int n = 0; n < 52; ++n) {
            const int e4 = SLOTW + (n * 64 + spx) * 4;
            uint4 pk = *reinterpret_cast<const uint4*>(&PU[e4]);
            uint2 v00, v01, v10, v11;
            if (pk.x != 0xFFFFFFFFu) {
                v00 = *reinterpret_cast<const uint2*>(Pb + (pk.x & 0xFFFFu) + c4b);
                v01 = *reinterpret_cast<const uint2*>(Pb + (pk.x >> 16)     + c4b);
                v10 = *reinterpret_cast<const uint2*>(Pb + (pk.y & 0xFFFFu) + c4b);
                v11 = *reinterpret_cast<const uint2*>(Pb + (pk.y >> 16)     + c4b);
            } else {
                uint32_t a00 = pk.y & 0xFFFFu, a11 = pk.y >> 16;
                uint32_t a01 = (a00 & ~63u) | (a11 & 63u);
                uint32_t a10 = (a11 & ~63u) | (a00 & 63u);
                v00 = xb2[(a00 << 4) + c4];
                v01 = xb2[(a01 << 4) + c4];
                v10 = xb2[(a10 << 4) + c4];
                v11 = xb2[(a11 << 4) + c4];
            }
            // pairs {v00[c], v01[c]} dotted with {m00,m01}; {v10[c],v11[c]} with {m10,m11}
            agg.x = fdot2u(pk.z, __builtin_amdgcn_perm(v01.x, v00.x, 0x05040100u), agg.x);
            agg.y = fdot2u(pk.z, __builtin_amdgcn_perm(v01.x, v00.x, 0x07060302u), agg.y);
            agg.z = fdot2u(pk.z, __builtin_amdgcn_perm(v01.y, v00.y, 0x05040100u), agg.z);
            agg.w = fdot2u(pk.z, __builtin_amdgcn_perm(v01.y, v00.y, 0x07060302u), agg.w);
            agg.x = fdot2u(pk.w, __builtin_amdgcn_perm(v11.x, v10.x, 0x05040100u), agg.x);
            agg.y = fdot2u(pk.w, __builtin_amdgcn_perm(v11.x, v10.x, 0x07060302u), agg.y);
            agg.z = fdot2u(pk.w, __builtin_amdgcn_perm(v11.y, v10.y, 0x05040100u), agg.z);
            agg.w = fdot2u(pk.w, __builtin_amdgcn_perm(v11.y, v10.y, 0x07060302u), agg.w);
        }
        // agg transposed [c][px] into TF (dead since B2)
        P[TFW + (c4 * 4 + 0) * 65 + spx] = agg.x;
        P[TFW + (c4 * 4 + 1) * 65 + spx] = agg.y;
        P[TFW + (c4 * 4 + 2) * 65 + spx] = agg.z;
        P[TFW + (c4 * 4 + 3) * 65 + spx] = agg.w;
    }
    __syncthreads();   // B5

    // ---- pc 1x1: TF -> TC ----
    {
        float acc[4];
        pw_acc<4>(P, TFW, lane, wv * 4, 64, pc_w, pc_b, acc);
        #pragma unroll
        for (int r = 0; r < 4; ++r) P[TCW + (wv * 4 + r) * 65 + lane] = acc[r];
    }
    __syncthreads();   // B6

    // ---- mlp1 (relu): TC -> TM ----
    {
        const int o0 = wv * 4;
        float acc[4];
        pw_acc<4>(P, TCW, lane, o0, 64, w1, b1, acc);
        #pragma unroll
        for (int r = 0; r < 4; ++r) P[TMW + (o0 + r) * 65 + lane] = fmaxf(acc[r], 0.0f);
    }
    __syncthreads();   // B7

    // ---- mlp2 + residual + coalesced NCHW store ----
    {
        const int o0 = wv * 4;
        float acc[4];
        pw_acc<4>(P, TMW, lane, o0, 64, w2, b2, acc);
        #pragma unroll
        for (int r = 0; r < 4; ++r) {
            int o = o0 + r;
            size_t idx = (((size_t)b * 64 + o) * 64 + y) * 64 + lane;
            out[idx] = acc[r] + x[idx];
        }
    }
}

extern "C" void kernel_launch(void* const* d_in, const int* in_sizes, int n_in,
                              void* d_out, int out_size, void* d_ws, size_t ws_size,
                              hipStream_t stream) {
    const float* x     = (const float*)d_in[0];
    const float* p_n   = (const float*)d_in[1];
    const float* dwf_w = (const float*)d_in[2];
    const float* dwf_b = (const float*)d_in[3];
    const float* pwf_w = (const float*)d_in[4];
    const float* pwf_b = (const float*)d_in[5];
    const float* dwc_w = (const float*)d_in[6];
    const float* dwc_b = (const float*)d_in[7];
    const float* pwc_w = (const float*)d_in[8];
    const float* pwc_b = (const float*)d_in[9];
    const float* dwm_w = (const float*)d_in[10];
    const float* dwm_b = (const float*)d_in[11];
    const float* pwm_w = (const float*)d_in[12];
    const float* pwm_b = (const float*)d_in[13];
    const float* pc_w  = (const float*)d_in[14];
    const float* pc_b  = (const float*)d_in[15];
    const float* w1    = (const float*)d_in[16];
    const float* b1    = (const float*)d_in[17];
    const float* w2    = (const float*)d_in[18];
    const float* b2    = (const float*)d_in[19];

    __half* xth = (__half*)d_ws;      // 2 MB NHWC fp16 copy of x
    float* outp = (float*)d_out;

    hipLaunchKernelGGL(transpose_half, dim3(BB * HH), dim3(256), 0, stream, x, xth);
    hipLaunchKernelGGL(crossd_main, dim3(BB * HH), dim3(1024), 0, stream,
                       xth, x, p_n,
                       dwf_w, dwf_b, pwf_w, pwf_b,
                       dwc_w, dwc_b, pwc_w, pwc_b,
                       dwm_w, dwm_b, pwm_w, pwm_b,
                       pc_w, pc_b, w1, b1, w2, b2, outp);
}